// Round 1
// baseline (507.336 us; speedup 1.0000x reference)
//
#include <hip/hip_runtime.h>
#include <hip/hip_bf16.h>

typedef __bf16 bf16_t;
typedef __bf16 bf16x8 __attribute__((ext_vector_type(8)));
typedef float  f32x4  __attribute__((ext_vector_type(4)));

#define DM      512      // model dim == K
#define NQKV    1536     // 3 * 512 concatenated output columns
#define TM      32       // tokens per block
#define THREADS 512      // 8 waves
#define CH      72       // LDS chunk stride: 64 data + 8 pad (bf16 elems)
#define QS      (24*CH + 8)  // per-token LDS stride = 1736 elems

// Pre-transposed bf16 weights: g_wt[N][k], N = mat*512 + n (q,k,v concat).
__device__ __align__(16) bf16_t g_wt[NQKV * DM];

// ---------------------------------------------------------------------------
// Kernel 1: transpose + convert W_q|W_k|W_v (fp32 [k][n]) -> g_wt (bf16 [n][k])
// ---------------------------------------------------------------------------
__global__ void prep_w(const float* __restrict__ Wq,
                       const float* __restrict__ Wk,
                       const float* __restrict__ Wv) {
    __shared__ float tile[32][33];              // +1 pad: conflict-free transpose
    int b   = blockIdx.x;                        // 3 * 16 * 16 = 768 blocks
    int mat = b >> 8;                            // /256
    int kt  = (b >> 4) & 15;
    int nt  = b & 15;
    const float* W = (mat == 0) ? Wq : ((mat == 1) ? Wk : Wv);
    int tx = threadIdx.x & 31, ty = threadIdx.x >> 5;   // 32 x 8
#pragma unroll
    for (int p = 0; p < 4; ++p) {
        int kk = p * 8 + ty;
        tile[kk][tx] = W[(kt * 32 + kk) * DM + nt * 32 + tx];
    }
    __syncthreads();
#pragma unroll
    for (int p = 0; p < 4; ++p) {
        int rn = p * 8 + ty;
        int N  = mat * 512 + nt * 32 + rn;
        g_wt[N * DM + kt * 32 + tx] = (bf16_t)tile[tx][rn];
    }
}

// ---------------------------------------------------------------------------
// Kernel 2: fused QKV projection (bf16 MFMA) + per-token cross-head attention
// ---------------------------------------------------------------------------
__global__ __launch_bounds__(THREADS, 2) void fused_mha(
    const float* __restrict__ x, float* __restrict__ out) {
    extern __shared__ char smem[];
    // xs  : bf16 [32][512] swizzled   -- lifetime: staging .. end of K-loop
    // qkv : bf16 [32][QS] chunked     -- lifetime: epilogue .. end (aliases xs)
    bf16_t* qkv = (bf16_t*)smem;

    const int tid  = threadIdx.x;
    const int lane = tid & 63;
    const int w    = tid >> 6;          // wave 0..7
    const long tok0 = (long)blockIdx.x * TM;

    // ---------------- stage x tile: fp32 global -> bf16 LDS (swizzled) ------
    for (int c = tid; c < TM * 64; c += THREADS) {
        int r  = c >> 6;                 // token row 0..31
        int k0 = (c & 63) << 3;          // k chunk of 8
        const float4* gp = (const float4*)(x + (tok0 + r) * DM + k0);
        float4 f0 = gp[0], f1 = gp[1];
        bf16x8 v;
        v[0] = (bf16_t)f0.x; v[1] = (bf16_t)f0.y;
        v[2] = (bf16_t)f0.z; v[3] = (bf16_t)f0.w;
        v[4] = (bf16_t)f1.x; v[5] = (bf16_t)f1.y;
        v[6] = (bf16_t)f1.z; v[7] = (bf16_t)f1.w;
        int byte = (r << 10) + (k0 << 1);
        byte ^= (r & 7) << 4;            // XOR-swizzle (G4: 1024B row stride)
        *(bf16x8*)(smem + byte) = v;
    }
    __syncthreads();

    // ---------------- GEMM: 32 x 1536 x 512, barrier-free K-loop ------------
    f32x4 acc[2][12];
#pragma unroll
    for (int rf = 0; rf < 2; ++rf)
#pragma unroll
        for (int cf = 0; cf < 12; ++cf)
            acc[rf][cf] = (f32x4){0.f, 0.f, 0.f, 0.f};

    const int kg = lane >> 4;            // 0..3 (k-group of the fragment)
    const int lr = lane & 15;
    const int swz = (lr & 7) << 4;       // same for row lr and row 16+lr
    const bf16_t* wtb = g_wt + (w * 192 + lr) * DM + kg * 8;

    for (int ks = 0; ks < 16; ++ks) {
        int kb = (ks * 32 + kg * 8) << 1;   // byte offset along k within a row
        bf16x8 a0 = *(const bf16x8*)(smem + ((( lr       << 10) + kb) ^ swz));
        bf16x8 a1 = *(const bf16x8*)(smem + ((((16 + lr) << 10) + kb) ^ swz));
        const bf16_t* wk = wtb + ks * 32;
#pragma unroll
        for (int cf = 0; cf < 12; ++cf) {
            bf16x8 bfrag = *(const bf16x8*)(wk + cf * 16 * DM);
            acc[0][cf] = __builtin_amdgcn_mfma_f32_16x16x32_bf16(a0, bfrag, acc[0][cf], 0, 0, 0);
            acc[1][cf] = __builtin_amdgcn_mfma_f32_16x16x32_bf16(a1, bfrag, acc[1][cf], 0, 0, 0);
        }
    }
    __syncthreads();   // xs dead beyond this point; qkv may overwrite it

    // ---------------- epilogue: acc -> qkv LDS (bf16, chunked layout) -------
    // C/D layout (m89/m91): col = lane&15, row = (lane>>4)*4 + reg
#pragma unroll
    for (int rf = 0; rf < 2; ++rf)
#pragma unroll
        for (int cf = 0; cf < 12; ++cf) {
            int n    = w * 192 + cf * 16 + lr;
            int noff = (n >> 6) * CH + (n & 63);
#pragma unroll
            for (int i = 0; i < 4; ++i) {
                int token = rf * 16 + kg * 4 + i;
                qkv[token * QS + noff] = (bf16_t)acc[rf][cf][i];
            }
        }
    __syncthreads();

    // ---------------- attention: 16 threads per token -----------------------
    int tok  = tid >> 4;
    int tj   = tid & 15;
    int h    = tj & 7;        // this thread's query head (score row)
    int half = tj >> 3;       // d-half 0/1
    int d0   = half * 32;
    const bf16_t* base = qkv + tok * QS;

    float qv[32];
    {
        const bf16_t* qp = base + h * CH + d0;
#pragma unroll
        for (int j = 0; j < 4; ++j) {
            bf16x8 q8 = *(const bf16x8*)(qp + 8 * j);
#pragma unroll
            for (int e = 0; e < 8; ++e) qv[8 * j + e] = (float)q8[e];
        }
    }

    float s[8];
#pragma unroll
    for (int t = 0; t < 8; ++t) {
        const bf16_t* kp = base + (8 + t) * CH + d0;
        float a = 0.f;
#pragma unroll
        for (int j = 0; j < 4; ++j) {
            bf16x8 k8 = *(const bf16x8*)(kp + 8 * j);
#pragma unroll
            for (int e = 0; e < 8; ++e) a += qv[8 * j + e] * (float)k8[e];
        }
        s[t] = a;
    }
    // combine the two d-halves (partner lane = lane^8, same token, same h)
#pragma unroll
    for (int t = 0; t < 8; ++t) s[t] += __shfl_xor(s[t], 8, 64);

    float m = s[0];
#pragma unroll
    for (int t = 1; t < 8; ++t) m = fmaxf(m, s[t]);
    float p[8], psum = 0.f;
#pragma unroll
    for (int t = 0; t < 8; ++t) {
        p[t] = exp2f((s[t] - m) * 1.44269504088896f);
        psum += p[t];
    }
    float inv = 1.0f / psum;

    float o[32];
#pragma unroll
    for (int e = 0; e < 32; ++e) o[e] = 0.f;
#pragma unroll
    for (int t = 0; t < 8; ++t) {
        float pt = p[t] * inv;
        const bf16_t* vp = base + (16 + t) * CH + d0;
#pragma unroll
        for (int j = 0; j < 4; ++j) {
            bf16x8 v8 = *(const bf16x8*)(vp + 8 * j);
#pragma unroll
            for (int e = 0; e < 8; ++e) o[8 * j + e] += pt * (float)v8[e];
        }
    }

    float* op = out + (tok0 + tok) * DM + h * 64 + d0;
#pragma unroll
    for (int j = 0; j < 8; ++j) {
        float4 o4 = {o[4 * j], o[4 * j + 1], o[4 * j + 2], o[4 * j + 3]};
        *(float4*)(op + 4 * j) = o4;
    }
}

// ---------------------------------------------------------------------------
extern "C" void kernel_launch(void* const* d_in, const int* in_sizes, int n_in,
                              void* d_out, int out_size, void* d_ws, size_t ws_size,
                              hipStream_t stream) {
    const float* x  = (const float*)d_in[0];
    const float* Wq = (const float*)d_in[1];
    const float* Wk = (const float*)d_in[2];
    const float* Wv = (const float*)d_in[3];
    float* out = (float*)d_out;

    int ntok = in_sizes[0] / DM;                  // 65536
    prep_w<<<768, 256, 0, stream>>>(Wq, Wk, Wv);
    size_t lds = (size_t)TM * QS * sizeof(bf16_t);   // 111,104 B
    fused_mha<<<ntok / TM, THREADS, lds, stream>>>(x, out);
}

// Round 2
// 491.167 us; speedup vs baseline: 1.0329x; 1.0329x over previous
//
#include <hip/hip_runtime.h>
#include <hip/hip_bf16.h>

typedef __bf16 bf16_t;
typedef __bf16 bf16x8 __attribute__((ext_vector_type(8)));
typedef float  f32x4  __attribute__((ext_vector_type(4)));

#define DM      512      // model dim == K
#define NQKV    1536     // 3 * 512 concatenated output columns
#define TM      32       // tokens per block
#define THREADS 512      // 8 waves
#define CH      72       // LDS chunk stride: 64 data + 8 pad (bf16 elems)
#define QS      (24*CH + 8)  // per-token LDS stride = 1736 elems

// Pre-transposed bf16 weights: g_wt[N][k], N = mat*512 + n (q,k,v concat).
// +32 columns of pad per nothing: we over-allocate one K-step (32 cols) so the
// branch-free prefetch of iteration ks=16 reads in-bounds garbage.
__device__ __align__(16) bf16_t g_wt[NQKV * (DM + 32)];
// NOTE: layout stays [N][DM] (stride DM); the pad is a flat tail region.
// Tail size needed: last row base (NQKV-1)*DM + 512..543 -> NQKV*DM + 32. OK.

// ---------------------------------------------------------------------------
// Kernel 1: transpose + convert W_q|W_k|W_v (fp32 [k][n]) -> g_wt (bf16 [n][k])
// ---------------------------------------------------------------------------
__global__ void prep_w(const float* __restrict__ Wq,
                       const float* __restrict__ Wk,
                       const float* __restrict__ Wv) {
    __shared__ float tile[32][33];              // +1 pad: conflict-free transpose
    int b   = blockIdx.x;                        // 3 * 16 * 16 = 768 blocks
    int mat = b >> 8;                            // /256
    int kt  = (b >> 4) & 15;
    int nt  = b & 15;
    const float* W = (mat == 0) ? Wq : ((mat == 1) ? Wk : Wv);
    int tx = threadIdx.x & 31, ty = threadIdx.x >> 5;   // 32 x 8
#pragma unroll
    for (int p = 0; p < 4; ++p) {
        int kk = p * 8 + ty;
        tile[kk][tx] = W[(kt * 32 + kk) * DM + nt * 32 + tx];
    }
    __syncthreads();
#pragma unroll
    for (int p = 0; p < 4; ++p) {
        int rn = p * 8 + ty;
        int N  = mat * 512 + nt * 32 + rn;
        g_wt[N * DM + kt * 32 + tx] = (bf16_t)tile[tx][rn];
    }
}

// ---------------------------------------------------------------------------
// Kernel 2: fused QKV projection (bf16 MFMA) + per-token cross-head attention
// ---------------------------------------------------------------------------
__global__ __launch_bounds__(THREADS, 2) void fused_mha(
    const float* __restrict__ x, float* __restrict__ out) {
    extern __shared__ char smem[];
    // xs  : bf16 [32][512] swizzled   -- lifetime: staging .. end of K-loop
    // qkv : bf16 [32][QS] chunked     -- lifetime: epilogue .. end (aliases xs)
    bf16_t* qkv = (bf16_t*)smem;

    const int tid  = threadIdx.x;
    const int lane = tid & 63;
    const int w    = tid >> 6;          // wave 0..7
    const long tok0 = (long)blockIdx.x * TM;

    // ---------------- stage x tile: fp32 global -> bf16 LDS (swizzled) ------
    for (int c = tid; c < TM * 64; c += THREADS) {
        int r  = c >> 6;                 // token row 0..31
        int k0 = (c & 63) << 3;          // k chunk of 8
        const float4* gp = (const float4*)(x + (tok0 + r) * DM + k0);
        float4 f0 = gp[0], f1 = gp[1];
        bf16x8 v;
        v[0] = (bf16_t)f0.x; v[1] = (bf16_t)f0.y;
        v[2] = (bf16_t)f0.z; v[3] = (bf16_t)f0.w;
        v[4] = (bf16_t)f1.x; v[5] = (bf16_t)f1.y;
        v[6] = (bf16_t)f1.z; v[7] = (bf16_t)f1.w;
        int byte = (r << 10) + (k0 << 1);
        byte ^= (r & 7) << 4;            // XOR-swizzle (G4: 1024B row stride)
        *(bf16x8*)(smem + byte) = v;
    }
    __syncthreads();

    // ---------------- GEMM: 32 x 1536 x 512, barrier-free K-loop ------------
    // Register double-buffered B prefetch: load iteration ks+1's 12 B-frags
    // while the matrix pipe chews on iteration ks (hides L2 latency; the
    // R1 version consumed loads in-iteration -> MfmaUtil 7.6%).
    f32x4 acc[2][12];
#pragma unroll
    for (int rf = 0; rf < 2; ++rf)
#pragma unroll
        for (int cf = 0; cf < 12; ++cf)
            acc[rf][cf] = (f32x4){0.f, 0.f, 0.f, 0.f};

    const int kg = lane >> 4;            // 0..3 (k-group of the fragment)
    const int lr = lane & 15;
    const int swz = (lr & 7) << 4;       // same for row lr and row 16+lr
    const bf16_t* wtb = g_wt + (w * 192 + lr) * DM + kg * 8;

    bf16x8 bnx[12];
#pragma unroll
    for (int cf = 0; cf < 12; ++cf)
        bnx[cf] = *(const bf16x8*)(wtb + cf * 16 * DM);

    for (int ks = 0; ks < 16; ++ks) {
        bf16x8 bcur[12];
#pragma unroll
        for (int cf = 0; cf < 12; ++cf) bcur[cf] = bnx[cf];

        // prefetch next K-step's B frags (ks==15 reads the in-bounds pad tail)
        const bf16_t* wkn = wtb + (ks + 1) * 32;
#pragma unroll
        for (int cf = 0; cf < 12; ++cf)
            bnx[cf] = *(const bf16x8*)(wkn + cf * 16 * DM);

        int kb = (ks * 32 + kg * 8) << 1;   // byte offset along k within a row
        bf16x8 a0 = *(const bf16x8*)(smem + ((( lr       << 10) + kb) ^ swz));
        bf16x8 a1 = *(const bf16x8*)(smem + ((((16 + lr) << 10) + kb) ^ swz));
#pragma unroll
        for (int cf = 0; cf < 12; ++cf) {
            acc[0][cf] = __builtin_amdgcn_mfma_f32_16x16x32_bf16(a0, bcur[cf], acc[0][cf], 0, 0, 0);
            acc[1][cf] = __builtin_amdgcn_mfma_f32_16x16x32_bf16(a1, bcur[cf], acc[1][cf], 0, 0, 0);
        }
    }
    __syncthreads();   // xs dead beyond this point; qkv may overwrite it

    // ---------------- epilogue: acc -> qkv LDS (bf16, chunked layout) -------
    // C/D layout (m89/m91): col = lane&15, row = (lane>>4)*4 + reg
#pragma unroll
    for (int rf = 0; rf < 2; ++rf)
#pragma unroll
        for (int cf = 0; cf < 12; ++cf) {
            int n    = w * 192 + cf * 16 + lr;
            int noff = (n >> 6) * CH + (n & 63);
#pragma unroll
            for (int i = 0; i < 4; ++i) {
                int token = rf * 16 + kg * 4 + i;
                qkv[token * QS + noff] = (bf16_t)acc[rf][cf][i];
            }
        }
    __syncthreads();

    // ---------------- attention: 16 threads per token -----------------------
    int tok  = tid >> 4;
    int tj   = tid & 15;
    int h    = tj & 7;        // this thread's query head (score row)
    int half = tj >> 3;       // d-half 0/1
    int d0   = half * 32;
    const bf16_t* base = qkv + tok * QS;

    float qv[32];
    {
        const bf16_t* qp = base + h * CH + d0;
#pragma unroll
        for (int j = 0; j < 4; ++j) {
            bf16x8 q8 = *(const bf16x8*)(qp + 8 * j);
#pragma unroll
            for (int e = 0; e < 8; ++e) qv[8 * j + e] = (float)q8[e];
        }
    }

    float s[8];
#pragma unroll
    for (int t = 0; t < 8; ++t) {
        const bf16_t* kp = base + (8 + t) * CH + d0;
        float a = 0.f;
#pragma unroll
        for (int j = 0; j < 4; ++j) {
            bf16x8 k8 = *(const bf16x8*)(kp + 8 * j);
#pragma unroll
            for (int e = 0; e < 8; ++e) a += qv[8 * j + e] * (float)k8[e];
        }
        s[t] = a;
    }
    // combine the two d-halves (partner lane = lane^8, same token, same h)
#pragma unroll
    for (int t = 0; t < 8; ++t) s[t] += __shfl_xor(s[t], 8, 64);

    float m = s[0];
#pragma unroll
    for (int t = 1; t < 8; ++t) m = fmaxf(m, s[t]);
    float p[8], psum = 0.f;
#pragma unroll
    for (int t = 0; t < 8; ++t) {
        p[t] = exp2f((s[t] - m) * 1.44269504088896f);
        psum += p[t];
    }
    float inv = 1.0f / psum;

    float o[32];
#pragma unroll
    for (int e = 0; e < 32; ++e) o[e] = 0.f;
#pragma unroll
    for (int t = 0; t < 8; ++t) {
        float pt = p[t] * inv;
        const bf16_t* vp = base + (16 + t) * CH + d0;
#pragma unroll
        for (int j = 0; j < 4; ++j) {
            bf16x8 v8 = *(const bf16x8*)(vp + 8 * j);
#pragma unroll
            for (int e = 0; e < 8; ++e) o[8 * j + e] += pt * (float)v8[e];
        }
    }

    float* op = out + (tok0 + tok) * DM + h * 64 + d0;
#pragma unroll
    for (int j = 0; j < 8; ++j) {
        float4 o4 = {o[4 * j], o[4 * j + 1], o[4 * j + 2], o[4 * j + 3]};
        *(float4*)(op + 4 * j) = o4;
    }
}

// ---------------------------------------------------------------------------
extern "C" void kernel_launch(void* const* d_in, const int* in_sizes, int n_in,
                              void* d_out, int out_size, void* d_ws, size_t ws_size,
                              hipStream_t stream) {
    const float* x  = (const float*)d_in[0];
    const float* Wq = (const float*)d_in[1];
    const float* Wk = (const float*)d_in[2];
    const float* Wv = (const float*)d_in[3];
    float* out = (float*)d_out;

    int ntok = in_sizes[0] / DM;                  // 65536
    prep_w<<<768, 256, 0, stream>>>(Wq, Wk, Wv);
    size_t lds = (size_t)TM * QS * sizeof(bf16_t);   // 111,104 B
    fused_mha<<<ntok / TM, THREADS, lds, stream>>>(x, out);
}

// Round 3
// 298.044 us; speedup vs baseline: 1.7022x; 1.6480x over previous
//
#include <hip/hip_runtime.h>
#include <hip/hip_bf16.h>

typedef __bf16 bf16_t;
typedef __bf16 bf16x8 __attribute__((ext_vector_type(8)));
typedef float  f32x4  __attribute__((ext_vector_type(4)));

#define DM    512
#define NQKV  1536
#define NTOK  65536

// Static device scratch (BSS, allocated at module load; fully rewritten each call)
__device__ __align__(16) bf16_t g_wt [(size_t)NQKV * DM];   // W^T, bf16 [n][k]
__device__ __align__(16) bf16_t g_xb [(size_t)NTOK * DM];   // x, bf16
__device__ __align__(16) bf16_t g_qkv[(size_t)NTOK * NQKV]; // qkv, bf16 [tok][1536]

typedef const void __attribute__((address_space(1)))* gas_t;
typedef void       __attribute__((address_space(3)))* sas_t;
__device__ __forceinline__ void gl_lds16(const void* g, void* s) {
    // async global->LDS, 16B/lane; LDS dest = wave-uniform base + lane*16
    __builtin_amdgcn_global_load_lds((gas_t)g, (sas_t)s, 16, 0, 0);
}

// ---------------------------------------------------------------------------
// Kernel 1: transpose + convert W_q|W_k|W_v (fp32 [k][n]) -> g_wt (bf16 [n][k])
// ---------------------------------------------------------------------------
__global__ void prep_w(const float* __restrict__ Wq,
                       const float* __restrict__ Wk,
                       const float* __restrict__ Wv) {
    __shared__ float tile[32][33];
    int b   = blockIdx.x;                 // 3*16*16 = 768
    int mat = b >> 8;
    int kt  = (b >> 4) & 15;
    int nt  = b & 15;
    const float* W = (mat == 0) ? Wq : ((mat == 1) ? Wk : Wv);
    int tx = threadIdx.x & 31, ty = threadIdx.x >> 5;
#pragma unroll
    for (int p = 0; p < 4; ++p) {
        int kk = p * 8 + ty;
        tile[kk][tx] = W[(kt * 32 + kk) * DM + nt * 32 + tx];
    }
    __syncthreads();
#pragma unroll
    for (int p = 0; p < 4; ++p) {
        int rn = p * 8 + ty;
        int N  = mat * 512 + nt * 32 + rn;
        g_wt[(size_t)N * DM + kt * 32 + tx] = (bf16_t)tile[tx][rn];
    }
}

// ---------------------------------------------------------------------------
// Kernel 2: x fp32 -> bf16
// ---------------------------------------------------------------------------
__global__ void cvt_x(const float* __restrict__ x) {
    size_t i = (size_t)blockIdx.x * blockDim.x + threadIdx.x;
    const size_t n8 = (size_t)NTOK * DM / 8;
    const size_t stride = (size_t)gridDim.x * blockDim.x;
    for (; i < n8; i += stride) {
        const float4* gp = (const float4*)(x + i * 8);
        float4 f0 = gp[0], f1 = gp[1];
        bf16x8 v;
        v[0] = (bf16_t)f0.x; v[1] = (bf16_t)f0.y;
        v[2] = (bf16_t)f0.z; v[3] = (bf16_t)f0.w;
        v[4] = (bf16_t)f1.x; v[5] = (bf16_t)f1.y;
        v[6] = (bf16_t)f1.z; v[7] = (bf16_t)f1.w;
        *(bf16x8*)(g_xb + i * 8) = v;
    }
}

// ---------------------------------------------------------------------------
// Kernel 3: qkv = xb @ wt^T   (M=65536, N=1536, K=512), m97-style 128^2 tile
// ---------------------------------------------------------------------------
__global__ __launch_bounds__(256) void gemm_qkv() {
    __shared__ __align__(16) char sm[32768];   // As 8K | Bs 8K ; epilogue: 32K C-tile
    char* As = sm;
    char* Bs = sm + 8192;

    int raw = blockIdx.x;                       // 6144 blocks
    int bid = (raw & 7) * 768 + (raw >> 3);     // XCD-chunked swizzle (6144%8==0)
    int mt  = bid / 12, nt = bid - mt * 12;     // n fastest: A-panel reuse in L2
    size_t m0 = (size_t)mt * 128;
    int    n0 = nt * 128;

    const int tid = threadIdx.x, l = tid & 63, w = tid >> 6;
    const int rS = w * 32 + (l >> 2);           // staging row (issue 0)
    const int cS = (l & 3) * 8;                 // staging col (elems)
    const int lr = l & 15, kg = l >> 4;
    const int wr = w >> 1, wc = w & 1;          // 2x2 wave grid, 64x64 out each

    f32x4 acc[4][4];
#pragma unroll
    for (int a = 0; a < 4; ++a)
#pragma unroll
        for (int b = 0; b < 4; ++b) acc[a][b] = (f32x4){0.f, 0.f, 0.f, 0.f};

    const bf16_t* xa = g_xb + (m0 + rS) * DM + cS;
    const bf16_t* wa = g_wt + (size_t)(n0 + rS) * DM + cS;

    for (int s = 0; s < 16; ++s) {
        const int k0 = s * 32;
        gl_lds16(xa + k0,           As + w * 2048);
        gl_lds16(xa + k0 + 16 * DM, As + w * 2048 + 1024);
        gl_lds16(wa + k0,           Bs + w * 2048);
        gl_lds16(wa + k0 + 16 * DM, Bs + w * 2048 + 1024);
        __syncthreads();            // compiler drains vmcnt before s_barrier

        bf16x8 af[4], bfr[4];
#pragma unroll
        for (int mi = 0; mi < 4; ++mi)
            af[mi] = *(const bf16x8*)(As + (wr * 64 + mi * 16 + lr) * 64 + kg * 16);
#pragma unroll
        for (int ni = 0; ni < 4; ++ni)
            bfr[ni] = *(const bf16x8*)(Bs + (wc * 64 + ni * 16 + lr) * 64 + kg * 16);
#pragma unroll
        for (int mi = 0; mi < 4; ++mi)
#pragma unroll
            for (int ni = 0; ni < 4; ++ni)
                acc[mi][ni] = __builtin_amdgcn_mfma_f32_16x16x32_bf16(
                    af[mi], bfr[ni], acc[mi][ni], 0, 0, 0);
        __syncthreads();
    }

    // epilogue: acc -> LDS bf16 [128][128], then coalesced 16B stores
    bf16_t* ct = (bf16_t*)sm;
#pragma unroll
    for (int mi = 0; mi < 4; ++mi)
#pragma unroll
        for (int ni = 0; ni < 4; ++ni) {
            int col = wc * 64 + ni * 16 + lr;   // C/D: col = lane&15
#pragma unroll
            for (int i = 0; i < 4; ++i) {
                int row = wr * 64 + mi * 16 + kg * 4 + i;  // row = (lane>>4)*4+reg
                ct[row * 128 + col] = (bf16_t)acc[mi][ni][i];
            }
        }
    __syncthreads();

    const int rr = tid >> 4, cc = (tid & 15) * 8;
#pragma unroll
    for (int j = 0; j < 8; ++j) {
        int row = j * 16 + rr;
        *(bf16x8*)(g_qkv + (m0 + row) * NQKV + n0 + cc) =
            *(const bf16x8*)(ct + row * 128 + cc);
    }
}

// ---------------------------------------------------------------------------
// Kernel 4: per-token cross-head attention. 16 tokens/block, K/V staged in LDS.
// ---------------------------------------------------------------------------
__global__ __launch_bounds__(256) void attn_x(float* __restrict__ out) {
    __shared__ __align__(16) char sm[32768];   // [tok][k 512 | v 512] bf16
    const int tid = threadIdx.x, l = tid & 63, w = tid >> 6;
    const size_t tok0 = (size_t)blockIdx.x * 16;
    const char* src = (const char*)g_qkv + tok0 * 3072;

    // stage k,v (2KB per token): 32 wave-issues of 1KB, 8 per wave
#pragma unroll
    for (int i = 0; i < 8; ++i) {
        int b = (w * 8 + i) << 10;
        gl_lds16(src + (b >> 11) * 3072 + 1024 + (b & 2047) + l * 16, sm + b);
    }

    const int tok = tid >> 4, tj = tid & 15, h = tj & 7, d0 = (tj >> 3) << 5;

    // q direct from global (overlaps the staging latency)
    float qv[32];
    {
        const bf16_t* qp = g_qkv + (tok0 + tok) * NQKV + h * 64 + d0;
#pragma unroll
        for (int j = 0; j < 4; ++j) {
            bf16x8 q8 = *(const bf16x8*)(qp + 8 * j);
#pragma unroll
            for (int e = 0; e < 8; ++e) qv[8 * j + e] = (float)q8[e];
        }
    }
    __syncthreads();

    const bf16_t* base = (const bf16_t*)sm + tok * 1024;
    float s[8];
#pragma unroll
    for (int t = 0; t < 8; ++t) {
        const bf16_t* kp = base + t * 64 + d0;
        float a = 0.f;
#pragma unroll
        for (int j = 0; j < 4; ++j) {
            bf16x8 k8 = *(const bf16x8*)(kp + 8 * j);
#pragma unroll
            for (int e = 0; e < 8; ++e) a += qv[8 * j + e] * (float)k8[e];
        }
        s[t] = a;
    }
#pragma unroll
    for (int t = 0; t < 8; ++t) s[t] += __shfl_xor(s[t], 8, 64);  // d-half combine

    float m = s[0];
#pragma unroll
    for (int t = 1; t < 8; ++t) m = fmaxf(m, s[t]);
    float p[8], psum = 0.f;
#pragma unroll
    for (int t = 0; t < 8; ++t) {
        p[t] = exp2f((s[t] - m) * 1.44269504088896f);
        psum += p[t];
    }
    float inv = 1.0f / psum;

    float o[32];
#pragma unroll
    for (int e = 0; e < 32; ++e) o[e] = 0.f;
#pragma unroll
    for (int t = 0; t < 8; ++t) {
        float pt = p[t] * inv;
        const bf16_t* vp = base + 512 + t * 64 + d0;
#pragma unroll
        for (int j = 0; j < 4; ++j) {
            bf16x8 v8 = *(const bf16x8*)(vp + 8 * j);
#pragma unroll
            for (int e = 0; e < 8; ++e) o[8 * j + e] += pt * (float)v8[e];
        }
    }

    float* op = out + (tok0 + tok) * DM + h * 64 + d0;
#pragma unroll
    for (int j = 0; j < 8; ++j) {
        float4 o4 = {o[4 * j], o[4 * j + 1], o[4 * j + 2], o[4 * j + 3]};
        *(float4*)(op + 4 * j) = o4;
    }
}

// ---------------------------------------------------------------------------
extern "C" void kernel_launch(void* const* d_in, const int* in_sizes, int n_in,
                              void* d_out, int out_size, void* d_ws, size_t ws_size,
                              hipStream_t stream) {
    const float* x  = (const float*)d_in[0];
    const float* Wq = (const float*)d_in[1];
    const float* Wk = (const float*)d_in[2];
    const float* Wv = (const float*)d_in[3];
    float* out = (float*)d_out;

    prep_w<<<768, 256, 0, stream>>>(Wq, Wk, Wv);
    cvt_x<<<2048, 256, 0, stream>>>(x);
    gemm_qkv<<<6144, 256, 0, stream>>>();        // 512 m-tiles x 12 n-tiles
    attn_x<<<4096, 256, 0, stream>>>(out);       // 16 tokens per block
}

// Round 4
// 264.978 us; speedup vs baseline: 1.9146x; 1.1248x over previous
//
#include <hip/hip_runtime.h>
#include <hip/hip_bf16.h>

typedef __bf16 bf16_t;
typedef __bf16 bf16x8 __attribute__((ext_vector_type(8)));
typedef float  f32x4  __attribute__((ext_vector_type(4)));

#define DM    512
#define NQKV  1536
#define NTOK  65536

// Static device scratch
__device__ __align__(16) bf16_t g_wt [(size_t)NQKV * DM];   // W^T, bf16 [n][k]
__device__ __align__(16) bf16_t g_xb [(size_t)NTOK * DM];   // x, bf16
__device__ __align__(16) bf16_t g_qkv[(size_t)NTOK * NQKV]; // qkv, bf16 [tok][1536]

typedef const void __attribute__((address_space(1)))* gas_t;
typedef void       __attribute__((address_space(3)))* sas_t;
__device__ __forceinline__ void gl_lds16(const void* g, void* s) {
    __builtin_amdgcn_global_load_lds((gas_t)g, (sas_t)s, 16, 0, 0);
}
#define MEMFENCE asm volatile("" ::: "memory")

// ---------------------------------------------------------------------------
// Kernel 1: transpose + convert W_q|W_k|W_v (fp32 [k][n]) -> g_wt (bf16 [n][k])
// ---------------------------------------------------------------------------
__global__ void prep_w(const float* __restrict__ Wq,
                       const float* __restrict__ Wk,
                       const float* __restrict__ Wv) {
    __shared__ float tile[32][33];
    int b   = blockIdx.x;                 // 3*16*16 = 768
    int mat = b >> 8;
    int kt  = (b >> 4) & 15;
    int nt  = b & 15;
    const float* W = (mat == 0) ? Wq : ((mat == 1) ? Wk : Wv);
    int tx = threadIdx.x & 31, ty = threadIdx.x >> 5;
#pragma unroll
    for (int p = 0; p < 4; ++p) {
        int kk = p * 8 + ty;
        tile[kk][tx] = W[(kt * 32 + kk) * DM + nt * 32 + tx];
    }
    __syncthreads();
#pragma unroll
    for (int p = 0; p < 4; ++p) {
        int rn = p * 8 + ty;
        int N  = mat * 512 + nt * 32 + rn;
        g_wt[(size_t)N * DM + kt * 32 + tx] = (bf16_t)tile[tx][rn];
    }
}

// ---------------------------------------------------------------------------
// Kernel 2: x fp32 -> bf16
// ---------------------------------------------------------------------------
__global__ void cvt_x(const float* __restrict__ x) {
    size_t i = (size_t)blockIdx.x * blockDim.x + threadIdx.x;
    const size_t n8 = (size_t)NTOK * DM / 8;
    const size_t stride = (size_t)gridDim.x * blockDim.x;
    for (; i < n8; i += stride) {
        const float4* gp = (const float4*)(x + i * 8);
        float4 f0 = gp[0], f1 = gp[1];
        bf16x8 v;
        v[0] = (bf16_t)f0.x; v[1] = (bf16_t)f0.y;
        v[2] = (bf16_t)f0.z; v[3] = (bf16_t)f0.w;
        v[4] = (bf16_t)f1.x; v[5] = (bf16_t)f1.y;
        v[6] = (bf16_t)f1.z; v[7] = (bf16_t)f1.w;
        *(bf16x8*)(g_xb + i * 8) = v;
    }
}

// ---------------------------------------------------------------------------
// Kernel 3: qkv = xb @ wt^T  (M=65536, N=1536, K=512)
// 256x256 tile, BK=64, 8 waves, 2x64KB LDS dbuf, 4-phase/K-tile counted-vmcnt
// schedule (T2 swizzle + T3/T4 phases + T5 setprio).
// ---------------------------------------------------------------------------
__global__ __launch_bounds__(512, 2) void gemm_qkv() {
    extern __shared__ char sm[];          // 131072 B: buf[2] x (A 32K | B 32K)

    const int tid = threadIdx.x;
    const int l   = tid & 63, w = tid >> 6;      // lane, wave 0..7
    const int lr  = l & 15, kg = l >> 4;         // frag row, k-group
    const int wr  = w >> 2, wc = w & 3;          // 2x4 wave grid -> 128x64/wave

    int raw = blockIdx.x;                         // 1536 blocks
    int bid = (raw & 7) * 192 + (raw >> 3);       // XCD swizzle (1536%8==0)
    int mt  = bid / 6, nt = bid - mt * 6;         // nt fastest: A-panel L2 reuse
    const size_t m0 = (size_t)mt * 256;
    const int    n0 = nt * 256;

    // ---- staging source (per-lane, chunk pre-swizzled: rule #21) ----------
    // issue ii covers rows ii*64 + w*8 + (l>>3); lane chunk (l&7)^(l>>3)
    const int srow   = w * 8 + (l >> 3);
    const int schunk = ((l & 7) ^ (l >> 3)) * 8;
    const bf16_t* gA = g_xb + (m0 + srow) * DM + schunk;
    const bf16_t* gB = g_wt + (size_t)(n0 + srow) * DM + schunk;
    const int dstW = w * 1024;                    // wave-uniform LDS slice

    auto stage = [&](int t, int half) {           // half 0=A, 1=B (4 issues)
        char* d = sm + (t & 1) * 65536 + half * 32768 + dstW;
        const bf16_t* s = (half ? gB : gA) + t * 64;
#pragma unroll
        for (int ii = 0; ii < 4; ++ii)
            gl_lds16(s + ii * 64 * DM, d + ii * 8192);
    };

    // ---- ds_read offsets (swizzled: chunk ^= row&7; row&7 == lr&7) --------
    const int c0   = ((kg ^ (lr & 7)) * 16);
    const int aoff = (wr * 128 + lr) * 128 + c0;            // + mi*2048, ^64 ks=1
    const int boff = 32768 + (wc * 64 + lr) * 128 + c0;     // + ni*2048, ^64 ks=1

    f32x4 acc[8][4];
#pragma unroll
    for (int a = 0; a < 8; ++a)
#pragma unroll
        for (int b = 0; b < 4; ++b) acc[a][b] = (f32x4){0.f, 0.f, 0.f, 0.f};

    // ---- prologue: stage K-tile 0, wait, barrier --------------------------
    stage(0, 0); stage(0, 1);
    asm volatile("s_waitcnt vmcnt(0)" ::: "memory");
    __builtin_amdgcn_s_barrier();
    MEMFENCE;

    bf16x8 bfrag[4][2];
#pragma unroll
    for (int t = 0; t < 8; ++t) {
        const int base = (t & 1) * 65536;
#pragma unroll
        for (int q = 0; q < 4; ++q) {
            // phase q: ds-load subtile (B all, once/tile; A mi-pair {2q,2q+1})
            if (q == 0) {
#pragma unroll
                for (int ni = 0; ni < 4; ++ni) {
                    int o = base + boff + ni * 2048;
                    bfrag[ni][0] = *(const bf16x8*)(sm + o);
                    bfrag[ni][1] = *(const bf16x8*)(sm + (o ^ 64));
                }
            }
            bf16x8 af[2][2];
#pragma unroll
            for (int mm = 0; mm < 2; ++mm) {
                int o = base + aoff + (q * 2 + mm) * 2048;
                af[mm][0] = *(const bf16x8*)(sm + o);
                af[mm][1] = *(const bf16x8*)(sm + (o ^ 64));
            }
            // stage next K-tile early (phases 0,1) -> ~3 phases of cover
            if (t < 7 && q < 2) stage(t + 1, q);

            __builtin_amdgcn_s_barrier();
            MEMFENCE;
            __builtin_amdgcn_s_setprio(1);
#pragma unroll
            for (int mm = 0; mm < 2; ++mm)
#pragma unroll
                for (int ni = 0; ni < 4; ++ni) {
                    acc[q*2+mm][ni] = __builtin_amdgcn_mfma_f32_16x16x32_bf16(
                        af[mm][0], bfrag[ni][0], acc[q*2+mm][ni], 0, 0, 0);
                    acc[q*2+mm][ni] = __builtin_amdgcn_mfma_f32_16x16x32_bf16(
                        af[mm][1], bfrag[ni][1], acc[q*2+mm][ni], 0, 0, 0);
                }
            __builtin_amdgcn_s_setprio(0);
            if (q == 3)  // once per K-tile; loads had phases 0..3 of cover
                asm volatile("s_waitcnt vmcnt(0)" ::: "memory");
            __builtin_amdgcn_s_barrier();
            MEMFENCE;
        }
    }

    // ---- epilogue: two-pass LDS roundtrip, [128][264] bf16 (conflict-free) -
    bf16_t* cds = (bf16_t*)sm;
#pragma unroll
    for (int p = 0; p < 2; ++p) {
        if (wr == p) {
#pragma unroll
            for (int mi = 0; mi < 8; ++mi)
#pragma unroll
                for (int ni = 0; ni < 4; ++ni)
#pragma unroll
                    for (int i = 0; i < 4; ++i)
                        cds[(mi * 16 + kg * 4 + i) * 264 + wc * 64 + ni * 16 + lr] =
                            (bf16_t)acc[mi][ni][i];
        }
        __builtin_amdgcn_s_barrier();
        MEMFENCE;
#pragma unroll
        for (int j = 0; j < 8; ++j) {
            int idx = j * 512 + tid;               // 0..4095
            int row = idx >> 5, ch = (idx & 31) * 8;
            *(bf16x8*)(g_qkv + (m0 + p * 128 + row) * NQKV + n0 + ch) =
                *(const bf16x8*)(cds + row * 264 + ch);
        }
        if (p == 0) { __builtin_amdgcn_s_barrier(); MEMFENCE; }
    }
}

// ---------------------------------------------------------------------------
// Kernel 4: per-token cross-head attention. 16 tokens/block, K/V staged in LDS.
// ---------------------------------------------------------------------------
__global__ __launch_bounds__(256) void attn_x(float* __restrict__ out) {
    __shared__ __align__(16) char sm[32768];   // [tok][k 512 | v 512] bf16
    const int tid = threadIdx.x, l = tid & 63, w = tid >> 6;
    const size_t tok0 = (size_t)blockIdx.x * 16;
    const char* src = (const char*)g_qkv + tok0 * 3072;

#pragma unroll
    for (int i = 0; i < 8; ++i) {
        int b = (w * 8 + i) << 10;
        gl_lds16(src + (b >> 11) * 3072 + 1024 + (b & 2047) + l * 16, sm + b);
    }

    const int tok = tid >> 4, tj = tid & 15, h = tj & 7, d0 = (tj >> 3) << 5;

    float qv[32];
    {
        const bf16_t* qp = g_qkv + (tok0 + tok) * NQKV + h * 64 + d0;
#pragma unroll
        for (int j = 0; j < 4; ++j) {
            bf16x8 q8 = *(const bf16x8*)(qp + 8 * j);
#pragma unroll
            for (int e = 0; e < 8; ++e) qv[8 * j + e] = (float)q8[e];
        }
    }
    __syncthreads();

    const bf16_t* base = (const bf16_t*)sm + tok * 1024;
    float s[8];
#pragma unroll
    for (int t = 0; t < 8; ++t) {
        const bf16_t* kp = base + t * 64 + d0;
        float a = 0.f;
#pragma unroll
        for (int j = 0; j < 4; ++j) {
            bf16x8 k8 = *(const bf16x8*)(kp + 8 * j);
#pragma unroll
            for (int e = 0; e < 8; ++e) a += qv[8 * j + e] * (float)k8[e];
        }
        s[t] = a;
    }
#pragma unroll
    for (int t = 0; t < 8; ++t) s[t] += __shfl_xor(s[t], 8, 64);

    float m = s[0];
#pragma unroll
    for (int t = 1; t < 8; ++t) m = fmaxf(m, s[t]);
    float p[8], psum = 0.f;
#pragma unroll
    for (int t = 0; t < 8; ++t) {
        p[t] = exp2f((s[t] - m) * 1.44269504088896f);
        psum += p[t];
    }
    float inv = 1.0f / psum;

    float o[32];
#pragma unroll
    for (int e = 0; e < 32; ++e) o[e] = 0.f;
#pragma unroll
    for (int t = 0; t < 8; ++t) {
        float pt = p[t] * inv;
        const bf16_t* vp = base + 512 + t * 64 + d0;
#pragma unroll
        for (int j = 0; j < 4; ++j) {
            bf16x8 v8 = *(const bf16x8*)(vp + 8 * j);
#pragma unroll
            for (int e = 0; e < 8; ++e) o[8 * j + e] += pt * (float)v8[e];
        }
    }

    float* op = out + (tok0 + tok) * DM + h * 64 + d0;
#pragma unroll
    for (int j = 0; j < 8; ++j) {
        float4 o4 = {o[4 * j], o[4 * j + 1], o[4 * j + 2], o[4 * j + 3]};
        *(float4*)(op + 4 * j) = o4;
    }
}

// ---------------------------------------------------------------------------
extern "C" void kernel_launch(void* const* d_in, const int* in_sizes, int n_in,
                              void* d_out, int out_size, void* d_ws, size_t ws_size,
                              hipStream_t stream) {
    const float* x  = (const float*)d_in[0];
    const float* Wq = (const float*)d_in[1];
    const float* Wk = (const float*)d_in[2];
    const float* Wv = (const float*)d_in[3];
    float* out = (float*)d_out;

    prep_w<<<768, 256, 0, stream>>>(Wq, Wk, Wv);
    cvt_x<<<2048, 256, 0, stream>>>(x);
    gemm_qkv<<<1536, 512, 131072, stream>>>();   // 256 m-tiles x 6 n-tiles
    attn_x<<<4096, 256, 0, stream>>>(out);       // 16 tokens per block
}